// Round 9
// baseline (315.191 us; speedup 1.0000x reference)
//
#include <hip/hip_runtime.h>
#include <hip/hip_bf16.h>

// Problem dims
#define BB 64
#define TT 128
#define FIN 12
#define HH 128

#define LOG2E 1.4426950408889634f
#define TWO_LOG2E 2.8853900817779268f

__device__ __forceinline__ float fexp2(float x) { return __builtin_amdgcn_exp2f(x); }
__device__ __forceinline__ float frcp(float x)  { return __builtin_amdgcn_rcpf(x); }

// tanh(x) = 1 - 2/(1+e^{2x}); correct limits at +/-inf via exp2->{inf,0}
__device__ __forceinline__ float tanh_f(float x) {
  return 1.0f - 2.0f * frcp(1.0f + fexp2(TWO_LOG2E * x));
}
__device__ __forceinline__ float sigm_f(float x) {
  return frcp(1.0f + fexp2(-LOG2E * x));
}

// DPP 8-lane sum (over lane bits 0..2). Pure VALU -- no DS traffic.
template <int CTRL>
__device__ __forceinline__ float dpp_addstage(float v) {
  int s = __builtin_amdgcn_update_dpp(0, __float_as_int(v), CTRL, 0xF, 0xF, true);
  return v + __int_as_float(s);
}
__device__ __forceinline__ float red8(float v) {
  v = dpp_addstage<0xB1>(v);   // quad_perm [1,0,3,2]: partner lane^1
  v = dpp_addstage<0x4E>(v);   // quad_perm [2,3,0,1]: partner lane^2
  v = dpp_addstage<0x141>(v);  // row_half_mirror: partner lane^7 -> 8-lane total
  return v;
}

#define FMA4S(acc, s, v) do { \
  acc.x = fmaf((s), (v).x, acc.x); \
  acc.y = fmaf((s), (v).y, acc.y); \
  acc.z = fmaf((s), (v).z, acc.z); \
  acc.w = fmaf((s), (v).w, acc.w); } while (0)

#define ACC4(hv, wv, a) do { \
  a = fmaf((hv).x, (wv).x, a); a = fmaf((hv).y, (wv).y, a); \
  a = fmaf((hv).z, (wv).z, a); a = fmaf((hv).w, (wv).w, a); } while (0)

// ---------------------------------------------------------------------------
// Shared LSTM phase body -- v6 SCALAR structure (measured 107.6/108.2 us).
// ---------------------------------------------------------------------------
__device__ __forceinline__ void lstm_phase(
    const float* __restrict__ Wih, const float* __restrict__ Whh,
    const float* __restrict__ bias, float* __restrict__ Hout /* b-offset applied */,
    float* __restrict__ xs, float (*hbuf)[160], float* __restrict__ hist,
    const int tid, const int q, const int i, float& c)
{
  const int xo   = (q < 4) ? 3 * q : 0;
  const float xz = (q < 4) ? 1.0f : 0.0f;

  float4 wg[4][4];
  #pragma unroll
  for (int g = 0; g < 4; ++g)
    #pragma unroll
    for (int j = 0; j < 4; ++j)
      wg[g][j] = *(const float4*)(Whh + ((g * HH + i) * HH) + 16 * q + 4 * j);

  float wx[4][3];
  #pragma unroll
  for (int g = 0; g < 4; ++g)
    #pragma unroll
    for (int j = 0; j < 3; ++j)
      wx[g][j] = Wih[(g * HH + i) * FIN + xo + j] * xz;

  const float bi = bias[i], bf = bias[HH + i], bg = bias[2 * HH + i], bo = bias[3 * HH + i];

  int ts = 0;
  #pragma unroll 1
  for (int half = 0; half < 2; ++half) {
    #pragma unroll 1
    for (int tt = 0; tt < 64; ++tt, ++ts) {
      const int t = half * 64 + tt;
      __syncthreads();  // h(t) ready in hbuf[ts&1]; hist copy reads done
      const float* hb = (const float*)hbuf[ts & 1] + q * 20;
      float4 h0 = *(const float4*)(hb + 0);
      float4 h1 = *(const float4*)(hb + 4);
      float4 h2 = *(const float4*)(hb + 8);
      float4 h3 = *(const float4*)(hb + 12);

      const float* xt = xs + t * FIN + xo;
      float x0 = xt[0], x1 = xt[1], x2 = xt[2];
      float ai = wx[0][0] * x0 + wx[0][1] * x1 + wx[0][2] * x2;
      float af = wx[1][0] * x0 + wx[1][1] * x1 + wx[1][2] * x2;
      float ag = wx[2][0] * x0 + wx[2][1] * x1 + wx[2][2] * x2;
      float ao = wx[3][0] * x0 + wx[3][1] * x1 + wx[3][2] * x2;

      ACC4(h0, wg[0][0], ai); ACC4(h0, wg[1][0], af); ACC4(h0, wg[2][0], ag); ACC4(h0, wg[3][0], ao);
      ACC4(h1, wg[0][1], ai); ACC4(h1, wg[1][1], af); ACC4(h1, wg[2][1], ag); ACC4(h1, wg[3][1], ao);
      ACC4(h2, wg[0][2], ai); ACC4(h2, wg[1][2], af); ACC4(h2, wg[2][2], ag); ACC4(h2, wg[3][2], ao);
      ACC4(h3, wg[0][3], ai); ACC4(h3, wg[1][3], af); ACC4(h3, wg[2][3], ag); ACC4(h3, wg[3][3], ao);

      ai = red8(ai); af = red8(af); ag = red8(ag); ao = red8(ao);

      if (q == 0) {
        float zi = sigm_f(ai + bi);
        float zf = sigm_f(af + bf);
        float zg = tanh_f(ag + bg);
        float zo = sigm_f(ao + bo);
        c = fmaf(zf, c, zi * zg);
        float hn = zo * tanh_f(c);
        hbuf[(ts + 1) & 1][(i >> 4) * 20 + (i & 15)] = hn;
        hist[tt * HH + i] = hn;   // LDS only -- no vm op in the step loop
      }
    }
    __syncthreads();  // hist writes visible
    {
      float4* dst = (float4*)(Hout + (size_t)(half * 64) * HH);
      const float4* src = (const float4*)hist;
      dst[tid]        = src[tid];
      dst[tid + 1024] = src[tid + 1024];
    }
  }
}

// ---------------------------------------------------------------------------
// K1a: encoder LSTM (64 blocks) -> encH.  cT stashed in decH row 0 (read by
// decoder before first overwrite); hT is encH row 127.
// ---------------------------------------------------------------------------
__global__ __launch_bounds__(1024, 4) void lstm_enc_kernel(
    const float* __restrict__ x,
    const float* __restrict__ eWih, const float* __restrict__ eWhh, const float* __restrict__ eb,
    float* __restrict__ encH, float* __restrict__ decH)
{
  const int b   = blockIdx.x;
  const int tid = threadIdx.x;
  const int q   = tid & 7;
  const int i   = tid >> 3;

  __shared__ __align__(16) float xs[TT * FIN];
  __shared__ __align__(16) float hbuf[2][160];
  __shared__ __align__(16) float hist[64 * HH];

  if (tid < (TT * FIN / 4))
    ((float4*)xs)[tid] = ((const float4*)(x + (size_t)b * TT * FIN))[tid];
  if (tid < 320) ((float*)hbuf)[tid] = 0.0f;
  float c = 0.0f;

  lstm_phase(eWih, eWhh, eb, encH + (size_t)b * TT * HH, xs, hbuf, hist, tid, q, i, c);

  if (q == 0) decH[(size_t)b * TT * HH + i] = c;   // cT handoff (row 0, pre-overwrite)
}

// ---------------------------------------------------------------------------
// K1b: heterogeneous grid (256 blocks x 1024 thr when y2buf present).
//  blocks 0..63:   decoder LSTM (h0 = encH row 127, c0 = decH row 0) -> decH.
//  blocks 64..191: Ep = exp2(2log2e * encH@W2^T) -> Pbuf.
//  blocks 192..255: y2[b,t,f] = encH[b,t,:]·outW2[f,:] -> y2buf (stride 16).
// P and y2 depend only on encH -> both fully hidden under the decoder.
// ---------------------------------------------------------------------------
__global__ __launch_bounds__(1024, 4) void lstm_dec_p_kernel(
    const float* __restrict__ x,
    const float* __restrict__ dWih, const float* __restrict__ dWhh, const float* __restrict__ db,
    const float* __restrict__ attnW, const float* __restrict__ outW,
    const float* __restrict__ encH,
    float* __restrict__ decH, float* __restrict__ Pbuf, float* __restrict__ y2buf)
{
  __shared__ __align__(16) float smem[12416];   // 48.5 KB, overlaid per path
  const int tid = threadIdx.x;

  if (blockIdx.x < 64) {
    // ---- decoder LSTM ----
    const int b = blockIdx.x;
    const int q = tid & 7;
    const int i = tid >> 3;
    float* xs           = smem;                          // 1536 floats
    float (*hbuf)[160]  = (float(*)[160])(smem + 1536);  // 320 floats
    float* hist         = smem + 1856;                   // 8192 floats

    if (tid < (TT * FIN / 4))
      ((float4*)xs)[tid] = ((const float4*)(x + (size_t)b * TT * FIN))[tid];
    if (tid < 128) {  // h0 = hT = encH row 127, skewed into hbuf[0]
      float hv = encH[((size_t)b * TT + 127) * HH + tid];
      hbuf[0][(tid >> 4) * 20 + (tid & 15)] = hv;
    }
    float c = 0.0f;
    if (q == 0) c = decH[(size_t)b * TT * HH + i];   // c0 = cT (stashed by enc)

    lstm_phase(dWih, dWhh, db, decH + (size_t)b * TT * HH, xs, hbuf, hist, tid, q, i, c);
  } else if (blockIdx.x < 192) {
    // ---- P projection (64-row tile) ----
    const int pb = blockIdx.x - 64;
    const int b  = pb & 63;
    const int r0 = (pb >> 6) * 64;
    float* WT = smem;          // [32][132] padded k-major W2^T quarter, 4224 floats
    float* Xt = smem + 4224;   // [64][128] encH tile, 8192 floats

    const float* X = encH + ((size_t)b * TT + r0) * HH;
    ((float4*)Xt)[tid]        = ((const float4*)X)[tid];
    ((float4*)Xt)[tid + 1024] = ((const float4*)X)[tid + 1024];

    const float* W = attnW + HH;   // W2 = attnW[:, H:2H], row stride 2H
    const int hq = tid & 31, rr = tid >> 5;   // rr 0..31 -> rows 2rr, 2rr+1
    const int h0 = 4 * hq;

    float4 acc0 = make_float4(0.f, 0.f, 0.f, 0.f);
    float4 acc1 = acc0;

    #pragma unroll 1
    for (int kb = 0; kb < 4; ++kb) {
      __syncthreads();
      { // stage 128h x 32k quarter, transposed, padded stride 132
        int h = tid >> 3, koff = (tid & 7) * 4;
        float4 v = *(const float4*)(W + h * 256 + kb * 32 + koff);
        WT[(koff + 0) * 132 + h] = v.x;
        WT[(koff + 1) * 132 + h] = v.y;
        WT[(koff + 2) * 132 + h] = v.z;
        WT[(koff + 3) * 132 + h] = v.w;
      }
      __syncthreads();
      const float* xr0 = Xt + (2 * rr) * 128 + kb * 32;
      const float* xr1 = xr0 + 128;
      #pragma unroll
      for (int k4 = 0; k4 < 32; k4 += 4) {
        float4 xa = *(const float4*)(xr0 + k4);
        float4 xb = *(const float4*)(xr1 + k4);
        float4 w0 = *(const float4*)&WT[(k4 + 0) * 132 + h0];
        float4 w1 = *(const float4*)&WT[(k4 + 1) * 132 + h0];
        float4 w2 = *(const float4*)&WT[(k4 + 2) * 132 + h0];
        float4 w3 = *(const float4*)&WT[(k4 + 3) * 132 + h0];
        FMA4S(acc0, xa.x, w0); FMA4S(acc0, xa.y, w1);
        FMA4S(acc0, xa.z, w2); FMA4S(acc0, xa.w, w3);
        FMA4S(acc1, xb.x, w0); FMA4S(acc1, xb.y, w1);
        FMA4S(acc1, xb.z, w2); FMA4S(acc1, xb.w, w3);
      }
    }
    acc0.x = fexp2(TWO_LOG2E * acc0.x); acc0.y = fexp2(TWO_LOG2E * acc0.y);
    acc0.z = fexp2(TWO_LOG2E * acc0.z); acc0.w = fexp2(TWO_LOG2E * acc0.w);
    acc1.x = fexp2(TWO_LOG2E * acc1.x); acc1.y = fexp2(TWO_LOG2E * acc1.y);
    acc1.z = fexp2(TWO_LOG2E * acc1.z); acc1.w = fexp2(TWO_LOG2E * acc1.w);
    float* O = Pbuf + ((size_t)b * TT + r0) * HH;
    *(float4*)(O + (2 * rr) * 128 + h0)     = acc0;
    *(float4*)(O + (2 * rr + 1) * 128 + h0) = acc1;
  } else if (y2buf) {
    // ---- y2 = encH @ outW2^T, one block per b (hidden under decoder) ----
    const int b = blockIdx.x - 192;
    float* w2l = smem;   // [12][132] outW2 rows, padded
    if (tid < 384) {
      int f = tid >> 5, k = (tid & 31) * 4;
      float4 wv = *(const float4*)(outW + f * 256 + 128 + k);
      *(float4*)&w2l[f * 132 + k] = wv;
    }
    __syncthreads();
    for (int j = tid; j < TT * 12; j += 1024) {
      int t = j / 12, f = j - 12 * t;
      const float* er = encH + ((size_t)b * TT + t) * HH;   // 12 lanes share a row (L1)
      const float* wr = w2l + f * 132;
      float a = 0.f;
      #pragma unroll 8
      for (int k = 0; k < 32; ++k) {
        float4 ev = *(const float4*)(er + 4 * k);
        float4 wv = *(const float4*)(wr + 4 * k);
        ACC4(ev, wv, a);
      }
      y2buf[b * (TT * 16) + t * 16 + f] = a;
    }
  }
}

// ---------------------------------------------------------------------------
// K2 (fallback only): Ea -> Abuf.  Used when workspace lacks y2buf room.
// ---------------------------------------------------------------------------
__global__ __launch_bounds__(256, 2) void projA_kernel(
    const float* __restrict__ decH, const float* __restrict__ attnW,
    const float* __restrict__ attnb, float* __restrict__ Abuf)
{
  const int b  = blockIdx.x & 63;
  const int r0 = (blockIdx.x >> 6) * 16;
  const int tid = threadIdx.x;

  __shared__ __align__(16) float WT[64 * 128];  // 32 KB: W1^T for a k-half
  __shared__ __align__(16) float Xt[16 * 128];  // 8 KB

  const float* X = decH + ((size_t)b * TT + r0) * HH;
  const float* W = attnW;   // W1 = attnW[:, :H], row stride 2H

  ((float4*)Xt)[tid]       = ((const float4*)X)[tid];
  ((float4*)Xt)[256 + tid] = ((const float4*)X)[256 + tid];

  const int hq = tid & 31, rr = tid >> 5;
  const int h0 = 4 * hq;

  float4 acc0 = *(const float4*)(attnb + h0);
  float4 acc1 = acc0;

  for (int kb = 0; kb < 2; ++kb) {
    __syncthreads();  // protect WT overwrite
    {
      int h = tid >> 1, koff = (tid & 1) * 32;
      #pragma unroll
      for (int j = 0; j < 8; ++j) {
        float4 v = *(const float4*)(W + h * 256 + kb * 64 + koff + 4 * j);
        int kp = koff + 4 * j;
        WT[(kp + 0) * 128 + h] = v.x;
        WT[(kp + 1) * 128 + h] = v.y;
        WT[(kp + 2) * 128 + h] = v.z;
        WT[(kp + 3) * 128 + h] = v.w;
      }
    }
    __syncthreads();
    const float* xr0 = Xt + (2 * rr) * 128 + kb * 64;
    const float* xr1 = xr0 + 128;
    #pragma unroll
    for (int k4 = 0; k4 < 64; k4 += 4) {
      float4 xa = *(const float4*)(xr0 + k4);
      float4 xb = *(const float4*)(xr1 + k4);
      float4 w0 = *(const float4*)&WT[(k4 + 0) * 128 + h0];
      float4 w1 = *(const float4*)&WT[(k4 + 1) * 128 + h0];
      float4 w2 = *(const float4*)&WT[(k4 + 2) * 128 + h0];
      float4 w3 = *(const float4*)&WT[(k4 + 3) * 128 + h0];
      FMA4S(acc0, xa.x, w0); FMA4S(acc0, xa.y, w1);
      FMA4S(acc0, xa.z, w2); FMA4S(acc0, xa.w, w3);
      FMA4S(acc1, xb.x, w0); FMA4S(acc1, xb.y, w1);
      FMA4S(acc1, xb.z, w2); FMA4S(acc1, xb.w, w3);
    }
  }
  acc0.x = fexp2(TWO_LOG2E * acc0.x); acc0.y = fexp2(TWO_LOG2E * acc0.y);
  acc0.z = fexp2(TWO_LOG2E * acc0.z); acc0.w = fexp2(TWO_LOG2E * acc0.w);
  acc1.x = fexp2(TWO_LOG2E * acc1.x); acc1.y = fexp2(TWO_LOG2E * acc1.y);
  acc1.z = fexp2(TWO_LOG2E * acc1.z); acc1.w = fexp2(TWO_LOG2E * acc1.w);
  float* O = Abuf + ((size_t)b * TT + r0) * HH;
  *(float4*)(O + (2 * rr) * 128 + h0)     = acc0;
  *(float4*)(O + (2 * rr + 1) * 128 + h0) = acc1;
}

#define AST 132  // padded row stride for a_lds / sc
#define Y2ST 20  // padded row stride for y2 (12 cols used)

// ---------------------------------------------------------------------------
// K3 v7 (main path): fused A-projection + attention + output.
// 256 blocks x 512 thr, 32 s-rows per block (1 block/CU, 91.5 KB LDS).
//  - Ea computed in-block with projA's staged-WT pattern (W1^T in buf, which
//    later holds Ep -- same 8192-word footprint, bitwise-identical dot order).
//    Removes the projA dispatch + the 4 MB Abuf round-trip.
//  - 32 rows/block: halves Pbuf staging traffic, amortizes barriers 2x.
//  - Energy: thread owns (s, t-quad) x all 128 h -> no h-split shfl reduce;
//    scores stay in registers through softmax (16-lane group reduce).
// ---------------------------------------------------------------------------
__global__ __launch_bounds__(512, 2) void attn_fused_kernel(
    const float* __restrict__ decH, const float* __restrict__ Pbuf,
    const float* __restrict__ y2buf,
    const float* __restrict__ attnW, const float* __restrict__ attnb,
    const float* __restrict__ vw, const float* __restrict__ outW,
    const float* __restrict__ outb, float* __restrict__ out)
{
  const int b  = blockIdx.x >> 2;
  const int s0 = (blockIdx.x & 3) * 32;
  const int tid = threadIdx.x;

  __shared__ __align__(16) float buf[64 * 128];    // 32 KB: W1^T (kb-half), then Ep^T-half
  __shared__ __align__(16) float a_lds[32 * AST];  // 16.9 KB: Ea tile
  __shared__ __align__(16) float sc[32 * AST];     // 16.9 KB: softmax weights
  __shared__ __align__(16) float dh[32 * 128];     // 16 KB: decH tile
  __shared__ __align__(16) float vl[HH];
  __shared__ __align__(16) float y2s[TT * Y2ST];   // 10 KB

  // ---- stage dh, vl, y2 ----
  ((float4*)dh)[tid]       = ((const float4*)(decH + ((size_t)b * TT + s0) * HH))[tid];
  ((float4*)dh)[tid + 512] = ((const float4*)(decH + ((size_t)b * TT + s0) * HH))[tid + 512];
  if (tid < 32) ((float4*)vl)[tid] = ((const float4*)vw)[tid];
  {
    float4 v = ((const float4*)(y2buf + (size_t)b * (TT * 16)))[tid];
    int t = tid >> 2, g = (tid & 3) * 4;
    *(float4*)&y2s[t * Y2ST + g] = v;
  }

  // ---- Ea = exp2(2log2e*(dh @ W1^T + attn_b)), projA pattern ----
  const int hq = tid & 31, rr = tid >> 5;   // rr 0..15 -> rows 2rr, 2rr+1 of 32
  const int h0 = 4 * hq;
  {
    float4 acc0 = *(const float4*)(attnb + h0);
    float4 acc1 = acc0;
    #pragma unroll 1
    for (int kb = 0; kb < 2; ++kb) {
      __syncthreads();  // kb0: dh/y2/vl staged; kb1: protect buf overwrite
      {
        // stage W1 rows [128][64k] transposed into buf[kp][h]
        int h = tid >> 2, koff = (tid & 3) * 16;
        #pragma unroll
        for (int j = 0; j < 4; ++j) {
          float4 v = *(const float4*)(attnW + h * 256 + kb * 64 + koff + 4 * j);
          int kp = koff + 4 * j;
          buf[(kp + 0) * 128 + h] = v.x;
          buf[(kp + 1) * 128 + h] = v.y;
          buf[(kp + 2) * 128 + h] = v.z;
          buf[(kp + 3) * 128 + h] = v.w;
        }
      }
      __syncthreads();
      const float* xr0 = dh + (2 * rr) * 128 + kb * 64;
      const float* xr1 = xr0 + 128;
      #pragma unroll
      for (int k4 = 0; k4 < 64; k4 += 4) {
        float4 xa = *(const float4*)(xr0 + k4);
        float4 xb = *(const float4*)(xr1 + k4);
        float4 w0 = *(const float4*)&buf[(k4 + 0) * 128 + h0];
        float4 w1 = *(const float4*)&buf[(k4 + 1) * 128 + h0];
        float4 w2 = *(const float4*)&buf[(k4 + 2) * 128 + h0];
        float4 w3 = *(const float4*)&buf[(k4 + 3) * 128 + h0];
        FMA4S(acc0, xa.x, w0); FMA4S(acc0, xa.y, w1);
        FMA4S(acc0, xa.z, w2); FMA4S(acc0, xa.w, w3);
        FMA4S(acc1, xb.x, w0); FMA4S(acc1, xb.y, w1);
        FMA4S(acc1, xb.z, w2); FMA4S(acc1, xb.w, w3);
      }
    }
    acc0.x = fexp2(TWO_LOG2E * acc0.x); acc0.y = fexp2(TWO_LOG2E * acc0.y);
    acc0.z = fexp2(TWO_LOG2E * acc0.z); acc0.w = fexp2(TWO_LOG2E * acc0.w);
    acc1.x = fexp2(TWO_LOG2E * acc1.x); acc1.y = fexp2(TWO_LOG2E * acc1.y);
    acc1.z = fexp2(TWO_LOG2E * acc1.z); acc1.w = fexp2(TWO_LOG2E * acc1.w);
    *(float4*)&a_lds[(2 * rr) * AST + h0]     = acc0;
    *(float4*)&a_lds[(2 * rr + 1) * AST + h0] = acc1;
  }

  const int uq = tid & 15;   // t-quad within half
  const int sl = tid >> 4;   // 0..31 decoder-step within tile

  // ---- energies: thread = (s=sl, t-quad=uq) over all 128 h ----
  float4 sA, sB;
  #pragma unroll 1
  for (int half = 0; half < 2; ++half) {
    __syncthreads();  // protect buf overwrite (W1 readers / prev half); a_lds writes done
    #pragma unroll
    for (int i = 0; i < 4; ++i) {
      int flat = i * 2048 + tid * 4;
      int tp = flat >> 7;        // 0..63
      int hh0 = flat & 127;
      float4 v = *(const float4*)(Pbuf + ((size_t)b * TT + half * 64 + tp) * HH + hh0);
      int tq = tp >> 2, tr = tp & 3;
      buf[(hh0 + 0) * 64 + 4 * ((tq ^ ((hh0 + 0) >> 2)) & 15) + tr] = v.x;
      buf[(hh0 + 1) * 64 + 4 * ((tq ^ ((hh0 + 1) >> 2)) & 15) + tr] = v.y;
      buf[(hh0 + 2) * 64 + 4 * ((tq ^ ((hh0 + 2) >> 2)) & 15) + tr] = v.z;
      buf[(hh0 + 3) * 64 + 4 * ((tq ^ ((hh0 + 3) >> 2)) & 15) + tr] = v.w;
    }
    __syncthreads();
    float4 acc = make_float4(0.f, 0.f, 0.f, 0.f);
    const float* earow = a_lds + sl * AST;
    #pragma unroll 4
    for (int h = 0; h < 128; h += 4) {
      float4 ea = *(const float4*)&earow[h];
      float4 va = *(const float4*)&vl[h];
      const int xoff = 4 * ((uq ^ ((h >> 2) & 15)) & 15);  // same for h..h+3
      float4 p0 = *(const float4*)&buf[(h + 0) * 64 + xoff];
      float4 p1 = *(const float4*)&buf[(h + 1) * 64 + xoff];
      float4 p2 = *(const float4*)&buf[(h + 2) * 64 + xoff];
      float4 p3 = *(const float4*)&buf[(h + 3) * 64 + xoff];
      acc.x = fmaf(va.x, frcp(fmaf(ea.x, p0.x, 1.f)), acc.x);
      acc.y = fmaf(va.x, frcp(fmaf(ea.x, p0.y, 1.f)), acc.y);
      acc.z = fmaf(va.x, frcp(fmaf(ea.x, p0.z, 1.f)), acc.z);
      acc.w = fmaf(va.x, frcp(fmaf(ea.x, p0.w, 1.f)), acc.w);
      acc.x = fmaf(va.y, frcp(fmaf(ea.y, p1.x, 1.f)), acc.x);
      acc.y = fmaf(va.y, frcp(fmaf(ea.y, p1.y, 1.f)), acc.y);
      acc.z = fmaf(va.y, frcp(fmaf(ea.y, p1.z, 1.f)), acc.z);
      acc.w = fmaf(va.y, frcp(fmaf(ea.y, p1.w, 1.f)), acc.w);
      acc.x = fmaf(va.z, frcp(fmaf(ea.z, p2.x, 1.f)), acc.x);
      acc.y = fmaf(va.z, frcp(fmaf(ea.z, p2.y, 1.f)), acc.y);
      acc.z = fmaf(va.z, frcp(fmaf(ea.z, p2.z, 1.f)), acc.z);
      acc.w = fmaf(va.z, frcp(fmaf(ea.z, p2.w, 1.f)), acc.w);
      acc.x = fmaf(va.w, frcp(fmaf(ea.w, p3.x, 1.f)), acc.x);
      acc.y = fmaf(va.w, frcp(fmaf(ea.w, p3.y, 1.f)), acc.y);
      acc.z = fmaf(va.w, frcp(fmaf(ea.w, p3.z, 1.f)), acc.z);
      acc.w = fmaf(va.w, frcp(fmaf(ea.w, p3.w, 1.f)), acc.w);
    }
    float4 o;
    o.x = -2.f * acc.x; o.y = -2.f * acc.y;
    o.z = -2.f * acc.z; o.w = -2.f * acc.w;
    if (half == 0) sA = o; else sB = o;
  }

  // ---- softmax over t (per s row; 16-lane group holds 128 scores) ----
  {
    float mx = fmaxf(fmaxf(fmaxf(sA.x, sA.y), fmaxf(sA.z, sA.w)),
                     fmaxf(fmaxf(sB.x, sB.y), fmaxf(sB.z, sB.w)));
    #pragma unroll
    for (int msk = 1; msk <= 8; msk <<= 1) mx = fmaxf(mx, __shfl_xor(mx, msk, 64));
    float4 eA, eB;
    eA.x = fexp2(LOG2E * (sA.x - mx)); eA.y = fexp2(LOG2E * (sA.y - mx));
    eA.z = fexp2(LOG2E * (sA.z - mx)); eA.w = fexp2(LOG2E * (sA.w - mx));
    eB.x = fexp2(LOG2E * (sB.x - mx)); eB.y = fexp2(LOG2E * (sB.y - mx));
    eB.z = fexp2(LOG2E * (sB.z - mx)); eB.w = fexp2(LOG2E * (sB.w - mx));
    float sm = ((eA.x + eA.y) + (eA.z + eA.w)) + ((eB.x + eB.y) + (eB.z + eB.w));
    #pragma unroll
    for (int msk = 1; msk <= 8; msk <<= 1) sm += __shfl_xor(sm, msk, 64);
    float r = frcp(sm);
    eA.x *= r; eA.y *= r; eA.z *= r; eA.w *= r;
    eB.x *= r; eB.y *= r; eB.z *= r; eB.w *= r;
    *(float4*)&sc[sl * AST + 4 * uq]      = eA;
    *(float4*)&sc[sl * AST + 64 + 4 * uq] = eB;
  }
  __syncthreads();  // sc complete

  // ---- out[b,s,f] = outb[f] + dh[s,:]·outW1[f,:] + sc[s,:]·y2[:,f] ----
  if (tid < 384) {
    int s = tid / 12, f = tid - 12 * (tid / 12);
    float acc = outb[f];
    const float4* w4 = (const float4*)(outW + f * 256);  // outW1 row (global/L1)
    const float4* d4 = (const float4*)(dh + s * 128);
    #pragma unroll
    for (int k = 0; k < 32; ++k) {
      float4 wv = w4[k], dv = d4[k];
      acc = fmaf(wv.x, dv.x, acc); acc = fmaf(wv.y, dv.y, acc);
      acc = fmaf(wv.z, dv.z, acc); acc = fmaf(wv.w, dv.w, acc);
    }
    const float* wrow = sc + s * AST;
    #pragma unroll 8
    for (int t = 0; t < TT; ++t)
      acc = fmaf(wrow[t], y2s[t * Y2ST + f], acc);
    out[((size_t)b * TT + s0 + s) * FIN + f] = acc;
  }
}

// ---------------------------------------------------------------------------
// K3 fallback (no y2 workspace): round-7 structure, 512 blocks x 16 rows.
// ---------------------------------------------------------------------------
__global__ __launch_bounds__(512, 2) void attn_kernel_fb(
    const float* __restrict__ encH, const float* __restrict__ decH,
    const float* __restrict__ Pbuf, const float* __restrict__ Abuf,
    const float* __restrict__ vw, const float* __restrict__ outW,
    const float* __restrict__ outb, float* __restrict__ out)
{
  const int b  = blockIdx.x >> 3;
  const int s0 = (blockIdx.x & 7) * 16;
  const int tid = threadIdx.x;

  __shared__ __align__(16) float buf[64 * 128];
  __shared__ __align__(16) float a_lds[16 * AST];
  __shared__ __align__(16) float sc[16 * AST];
  __shared__ __align__(16) float dh[16 * 128];
  __shared__ __align__(16) float vl[HH];
  __shared__ __align__(16) float y2s[TT * Y2ST];
  __shared__ __align__(16) float w2l[12 * AST];

  ((float4*)dh)[tid] = ((const float4*)(decH + ((size_t)b * TT + s0) * HH))[tid];
  if (tid < 32) ((float4*)vl)[tid] = ((const float4*)vw)[tid];
  {
    int r = tid >> 5, c4 = (tid & 31) * 4;
    float4 av = *(const float4*)(Abuf + ((size_t)b * TT + s0 + r) * HH + c4);
    *(float4*)&a_lds[r * AST + c4] = av;
  }
  if (tid < 384) {
    int f = tid >> 5, k = (tid & 31) * 4;
    float4 wv = *(const float4*)(outW + f * 256 + 128 + k);
    *(float4*)&w2l[f * AST + k] = wv;
  }

  const int u  = tid & 31;
  const int sl = tid >> 5;
  const int uq = u & 15;
  const int uh = u >> 4;

  for (int half = 0; half < 2; ++half) {
    const int tbase = half * 64;
    __syncthreads();
    #pragma unroll
    for (int i = 0; i < 4; ++i) {
      int flat = i * 2048 + tid * 4;
      int tp = flat >> 7;
      int h0 = flat & 127;
      float4 v = *(const float4*)(Pbuf + ((size_t)b * TT + tbase + tp) * HH + h0);
      int tq = tp >> 2, tr = tp & 3;
      buf[(h0 + 0) * 64 + 4 * ((tq ^ ((h0 + 0) >> 2)) & 15) + tr] = v.x;
      buf[(h0 + 1) * 64 + 4 * ((tq ^ ((h0 + 1) >> 2)) & 15) + tr] = v.y;
      buf[(h0 + 2) * 64 + 4 * ((tq ^ ((h0 + 2) >> 2)) & 15) + tr] = v.z;
      buf[(h0 + 3) * 64 + 4 * ((tq ^ ((h0 + 3) >> 2)) & 15) + tr] = v.w;
    }
    __syncthreads();
    float4 acc = make_float4(0.f, 0.f, 0.f, 0.f);
    const float* earow = a_lds + sl * AST;
    #pragma unroll 4
    for (int hh = 0; hh < 64; hh += 4) {
      const int h = uh * 64 + hh;
      float4 ea = *(const float4*)&earow[h];
      float4 va = *(const float4*)&vl[h];
      const int xoff = 4 * ((uq ^ ((h >> 2) & 15)) & 15);
      float4 p0 = *(const float4*)&buf[(h + 0) * 64 + xoff];
      float4 p1 = *(const float4*)&buf[(h + 1) * 64 + xoff];
      float4 p2 = *(const float4*)&buf[(h + 2) * 64 + xoff];
      float4 p3 = *(const float4*)&buf[(h + 3) * 64 + xoff];
      acc.x = fmaf(va.x, frcp(fmaf(ea.x, p0.x, 1.f)), acc.x);
      acc.y = fmaf(va.x, frcp(fmaf(ea.x, p0.y, 1.f)), acc.y);
      acc.z = fmaf(va.x, frcp(fmaf(ea.x, p0.z, 1.f)), acc.z);
      acc.w = fmaf(va.x, frcp(fmaf(ea.x, p0.w, 1.f)), acc.w);
      acc.x = fmaf(va.y, frcp(fmaf(ea.y, p1.x, 1.f)), acc.x);
      acc.y = fmaf(va.y, frcp(fmaf(ea.y, p1.y, 1.f)), acc.y);
      acc.z = fmaf(va.y, frcp(fmaf(ea.y, p1.z, 1.f)), acc.z);
      acc.w = fmaf(va.y, frcp(fmaf(ea.y, p1.w, 1.f)), acc.w);
      acc.x = fmaf(va.z, frcp(fmaf(ea.z, p2.x, 1.f)), acc.x);
      acc.y = fmaf(va.z, frcp(fmaf(ea.z, p2.y, 1.f)), acc.y);
      acc.z = fmaf(va.z, frcp(fmaf(ea.z, p2.z, 1.f)), acc.z);
      acc.w = fmaf(va.z, frcp(fmaf(ea.z, p2.w, 1.f)), acc.w);
      acc.x = fmaf(va.w, frcp(fmaf(ea.w, p3.x, 1.f)), acc.x);
      acc.y = fmaf(va.w, frcp(fmaf(ea.w, p3.y, 1.f)), acc.y);
      acc.z = fmaf(va.w, frcp(fmaf(ea.w, p3.z, 1.f)), acc.z);
      acc.w = fmaf(va.w, frcp(fmaf(ea.w, p3.w, 1.f)), acc.w);
    }
    acc.x += __shfl_xor(acc.x, 16, 64);
    acc.y += __shfl_xor(acc.y, 16, 64);
    acc.z += __shfl_xor(acc.z, 16, 64);
    acc.w += __shfl_xor(acc.w, 16, 64);
    if (uh == 0) {
      float4 o;
      o.x = -2.f * acc.x; o.y = -2.f * acc.y;
      o.z = -2.f * acc.z; o.w = -2.f * acc.w;
      *(float4*)&sc[sl * AST + tbase + 4 * uq] = o;
    }
  }
  __syncthreads();

  {
    float4 sv = *(const float4*)&sc[sl * AST + 4 * u];
    float mx = fmaxf(fmaxf(sv.x, sv.y), fmaxf(sv.z, sv.w));
    #pragma unroll
    for (int msk = 1; msk <= 16; msk <<= 1) mx = fmaxf(mx, __shfl_xor(mx, msk, 64));
    float4 e;
    e.x = fexp2(LOG2E * (sv.x - mx));
    e.y = fexp2(LOG2E * (sv.y - mx));
    e.z = fexp2(LOG2E * (sv.z - mx));
    e.w = fexp2(LOG2E * (sv.w - mx));
    float sm = (e.x + e.y) + (e.z + e.w);
    #pragma unroll
    for (int msk = 1; msk <= 16; msk <<= 1) sm += __shfl_xor(sm, msk, 64);
    float r = frcp(sm);
    e.x *= r; e.y *= r; e.z *= r; e.w *= r;
    *(float4*)&sc[sl * AST + 4 * u] = e;
  }

  // y2 in-block (no y2buf)
  for (int half = 0; half < 2; ++half) {
    const int tbase = half * 64;
    __syncthreads();
    #pragma unroll
    for (int i = 0; i < 4; ++i) {
      int flat = i * 2048 + tid * 4;
      int tp = flat >> 7;
      int hh0 = flat & 127;
      *(float4*)&buf[tp * 128 + hh0] =
          *(const float4*)(encH + ((size_t)b * TT + tbase + tp) * HH + hh0);
    }
    __syncthreads();
    {
      int j = tid;
      int t = j / 12, f = j - 12 * t;
      float a = 0.f;
      const float* br = buf + t * 128;
      const float* wr = w2l + f * AST;
      #pragma unroll 8
      for (int k = 0; k < 32; ++k) {
        float4 bv = *(const float4*)(br + 4 * k);
        float4 wv = *(const float4*)(wr + 4 * k);
        ACC4(bv, wv, a);
      }
      y2s[(tbase + t) * Y2ST + f] = a;
      if (tid < 256) {
        int j2 = tid + 512;
        int t2 = j2 / 12, f2 = j2 - 12 * t2;
        float a2 = 0.f;
        const float* br2 = buf + t2 * 128;
        const float* wr2 = w2l + f2 * AST;
        #pragma unroll 8
        for (int k = 0; k < 32; ++k) {
          float4 bv = *(const float4*)(br2 + 4 * k);
          float4 wv = *(const float4*)(wr2 + 4 * k);
          ACC4(bv, wv, a2);
        }
        y2s[(tbase + t2) * Y2ST + f2] = a2;
      }
    }
  }
  __syncthreads();

  if (tid < 192) {
    int s = tid / 12, f = tid - 12 * (tid / 12);
    float acc = outb[f];
    const float4* w4 = (const float4*)(outW + f * 256);
    const float4* d4 = (const float4*)(dh + s * 128);
    #pragma unroll
    for (int k = 0; k < 32; ++k) {
      float4 wv = w4[k], dv = d4[k];
      acc = fmaf(wv.x, dv.x, acc); acc = fmaf(wv.y, dv.y, acc);
      acc = fmaf(wv.z, dv.z, acc); acc = fmaf(wv.w, dv.w, acc);
    }
    const float* wrow = sc + s * AST;
    #pragma unroll 8
    for (int t = 0; t < TT; ++t)
      acc = fmaf(wrow[t], y2s[t * Y2ST + f], acc);
    out[((size_t)b * TT + s0 + s) * FIN + f] = acc;
  }
}

// ---------------------------------------------------------------------------
extern "C" void kernel_launch(void* const* d_in, const int* in_sizes, int n_in,
                              void* d_out, int out_size, void* d_ws, size_t ws_size,
                              hipStream_t stream)
{
  const float* x     = (const float*)d_in[0];
  const float* eWih  = (const float*)d_in[1];
  const float* eWhh  = (const float*)d_in[2];
  const float* eb    = (const float*)d_in[3];
  const float* dWih  = (const float*)d_in[4];
  const float* dWhh  = (const float*)d_in[5];
  const float* db    = (const float*)d_in[6];
  const float* attnW = (const float*)d_in[7];
  const float* attnb = (const float*)d_in[8];
  const float* vw    = (const float*)d_in[9];
  const float* outW  = (const float*)d_in[10];
  const float* outb  = (const float*)d_in[11];
  float* out = (float*)d_out;

  float* ws   = (float*)d_ws;
  const size_t SEG = (size_t)BB * TT * HH;  // 1,048,576 floats = 4 MB
  float* encH = ws;
  float* decH = ws + SEG;
  float* Pbuf = ws + 2 * SEG;   // Ep = exp2(2log2e * P)
  float* Abuf = ws + 3 * SEG;   // fallback only
  float* y2buf = ws + 4 * SEG;  // [BB][TT][16] y2

  const size_t need_bytes = (4 * SEG + (size_t)BB * TT * 16) * sizeof(float);
  const bool have_y2 = ws_size >= need_bytes;

  lstm_enc_kernel<<<64, 1024, 0, stream>>>(x, eWih, eWhh, eb, encH, decH);
  if (have_y2) {
    lstm_dec_p_kernel<<<256, 1024, 0, stream>>>(x, dWih, dWhh, db, attnW, outW,
                                                encH, decH, Pbuf, y2buf);
    attn_fused_kernel<<<256, 512, 0, stream>>>(decH, Pbuf, y2buf, attnW, attnb,
                                               vw, outW, outb, out);
  } else {
    lstm_dec_p_kernel<<<192, 1024, 0, stream>>>(x, dWih, dWhh, db, attnW, outW,
                                                encH, decH, Pbuf, nullptr);
    projA_kernel<<<512, 256, 0, stream>>>(decH, attnW, attnb, Abuf);
    attn_kernel_fb<<<512, 512, 0, stream>>>(encH, decH, Pbuf, Abuf,
                                            vw, outW, outb, out);
  }
}

// Round 10
// 314.761 us; speedup vs baseline: 1.0014x; 1.0014x over previous
//
#include <hip/hip_runtime.h>
#include <hip/hip_bf16.h>

// Problem dims
#define BB 64
#define TT 128
#define FIN 12
#define HH 128

#define LOG2E 1.4426950408889634f
#define TWO_LOG2E 2.8853900817779268f

__device__ __forceinline__ float fexp2(float x) { return __builtin_amdgcn_exp2f(x); }
__device__ __forceinline__ float frcp(float x)  { return __builtin_amdgcn_rcpf(x); }

// tanh(x) = 1 - 2/(1+e^{2x}); correct limits at +/-inf via exp2->{inf,0}
__device__ __forceinline__ float tanh_f(float x) {
  return 1.0f - 2.0f * frcp(1.0f + fexp2(TWO_LOG2E * x));
}
__device__ __forceinline__ float sigm_f(float x) {
  return frcp(1.0f + fexp2(-LOG2E * x));
}

// DPP 8-lane sum (over lane bits 0..2). Pure VALU -- no DS traffic.
template <int CTRL>
__device__ __forceinline__ float dpp_addstage(float v) {
  int s = __builtin_amdgcn_update_dpp(0, __float_as_int(v), CTRL, 0xF, 0xF, true);
  return v + __int_as_float(s);
}
__device__ __forceinline__ float red8(float v) {
  v = dpp_addstage<0xB1>(v);   // quad_perm [1,0,3,2]: partner lane^1
  v = dpp_addstage<0x4E>(v);   // quad_perm [2,3,0,1]: partner lane^2
  v = dpp_addstage<0x141>(v);  // row_half_mirror: partner lane^7 -> 8-lane total
  return v;
}

#define FMA4S(acc, s, v) do { \
  acc.x = fmaf((s), (v).x, acc.x); \
  acc.y = fmaf((s), (v).y, acc.y); \
  acc.z = fmaf((s), (v).z, acc.z); \
  acc.w = fmaf((s), (v).w, acc.w); } while (0)

#define ACC4(hv, wv, a) do { \
  a = fmaf((hv).x, (wv).x, a); a = fmaf((hv).y, (wv).y, a); \
  a = fmaf((hv).z, (wv).z, a); a = fmaf((hv).w, (wv).w, a); } while (0)

// ---------------------------------------------------------------------------
// Shared LSTM phase body -- v6 SCALAR structure (measured 107.6/108.2 us).
// ---------------------------------------------------------------------------
__device__ __forceinline__ void lstm_phase(
    const float* __restrict__ Wih, const float* __restrict__ Whh,
    const float* __restrict__ bias, float* __restrict__ Hout /* b-offset applied */,
    float* __restrict__ xs, float (*hbuf)[160], float* __restrict__ hist,
    const int tid, const int q, const int i, float& c)
{
  const int xo   = (q < 4) ? 3 * q : 0;
  const float xz = (q < 4) ? 1.0f : 0.0f;

  float4 wg[4][4];
  #pragma unroll
  for (int g = 0; g < 4; ++g)
    #pragma unroll
    for (int j = 0; j < 4; ++j)
      wg[g][j] = *(const float4*)(Whh + ((g * HH + i) * HH) + 16 * q + 4 * j);

  float wx[4][3];
  #pragma unroll
  for (int g = 0; g < 4; ++g)
    #pragma unroll
    for (int j = 0; j < 3; ++j)
      wx[g][j] = Wih[(g * HH + i) * FIN + xo + j] * xz;

  const float bi = bias[i], bf = bias[HH + i], bg = bias[2 * HH + i], bo = bias[3 * HH + i];

  int ts = 0;
  #pragma unroll 1
  for (int half = 0; half < 2; ++half) {
    #pragma unroll 1
    for (int tt = 0; tt < 64; ++tt, ++ts) {
      const int t = half * 64 + tt;
      __syncthreads();  // h(t) ready in hbuf[ts&1]; hist copy reads done
      const float* hb = (const float*)hbuf[ts & 1] + q * 20;
      float4 h0 = *(const float4*)(hb + 0);
      float4 h1 = *(const float4*)(hb + 4);
      float4 h2 = *(const float4*)(hb + 8);
      float4 h3 = *(const float4*)(hb + 12);

      const float* xt = xs + t * FIN + xo;
      float x0 = xt[0], x1 = xt[1], x2 = xt[2];
      float ai = wx[0][0] * x0 + wx[0][1] * x1 + wx[0][2] * x2;
      float af = wx[1][0] * x0 + wx[1][1] * x1 + wx[1][2] * x2;
      float ag = wx[2][0] * x0 + wx[2][1] * x1 + wx[2][2] * x2;
      float ao = wx[3][0] * x0 + wx[3][1] * x1 + wx[3][2] * x2;

      ACC4(h0, wg[0][0], ai); ACC4(h0, wg[1][0], af); ACC4(h0, wg[2][0], ag); ACC4(h0, wg[3][0], ao);
      ACC4(h1, wg[0][1], ai); ACC4(h1, wg[1][1], af); ACC4(h1, wg[2][1], ag); ACC4(h1, wg[3][1], ao);
      ACC4(h2, wg[0][2], ai); ACC4(h2, wg[1][2], af); ACC4(h2, wg[2][2], ag); ACC4(h2, wg[3][2], ao);
      ACC4(h3, wg[0][3], ai); ACC4(h3, wg[1][3], af); ACC4(h3, wg[2][3], ag); ACC4(h3, wg[3][3], ao);

      ai = red8(ai); af = red8(af); ag = red8(ag); ao = red8(ao);

      if (q == 0) {
        float zi = sigm_f(ai + bi);
        float zf = sigm_f(af + bf);
        float zg = tanh_f(ag + bg);
        float zo = sigm_f(ao + bo);
        c = fmaf(zf, c, zi * zg);
        float hn = zo * tanh_f(c);
        hbuf[(ts + 1) & 1][(i >> 4) * 20 + (i & 15)] = hn;
        hist[tt * HH + i] = hn;   // LDS only -- no vm op in the step loop
      }
    }
    __syncthreads();  // hist writes visible
    {
      float4* dst = (float4*)(Hout + (size_t)(half * 64) * HH);
      const float4* src = (const float4*)hist;
      dst[tid]        = src[tid];
      dst[tid + 1024] = src[tid + 1024];
    }
  }
}

// ---------------------------------------------------------------------------
// K1a: encoder LSTM (64 blocks) -> encH.  cT stashed in decH row 0 (read by
// decoder before first overwrite); hT is encH row 127.
// ---------------------------------------------------------------------------
__global__ __launch_bounds__(1024, 4) void lstm_enc_kernel(
    const float* __restrict__ x,
    const float* __restrict__ eWih, const float* __restrict__ eWhh, const float* __restrict__ eb,
    float* __restrict__ encH, float* __restrict__ decH)
{
  const int b   = blockIdx.x;
  const int tid = threadIdx.x;
  const int q   = tid & 7;
  const int i   = tid >> 3;

  __shared__ __align__(16) float xs[TT * FIN];
  __shared__ __align__(16) float hbuf[2][160];
  __shared__ __align__(16) float hist[64 * HH];

  if (tid < (TT * FIN / 4))
    ((float4*)xs)[tid] = ((const float4*)(x + (size_t)b * TT * FIN))[tid];
  if (tid < 320) ((float*)hbuf)[tid] = 0.0f;
  float c = 0.0f;

  lstm_phase(eWih, eWhh, eb, encH + (size_t)b * TT * HH, xs, hbuf, hist, tid, q, i, c);

  if (q == 0) decH[(size_t)b * TT * HH + i] = c;   // cT handoff (row 0, pre-overwrite)
}

// ---------------------------------------------------------------------------
// K1b: heterogeneous grid (256 blocks x 1024 thr when y2buf present).
//  blocks 0..63:   decoder LSTM (h0 = encH row 127, c0 = decH row 0) -> decH.
//  blocks 64..191: Ep = exp2(2log2e * encH@W2^T) -> Pbuf.
//  blocks 192..255: y2[b,t,f] = encH[b,t,:]·outW2[f,:] -> y2buf (stride 16).
// P and y2 depend only on encH -> both fully hidden under the decoder.
// ---------------------------------------------------------------------------
__global__ __launch_bounds__(1024, 4) void lstm_dec_p_kernel(
    const float* __restrict__ x,
    const float* __restrict__ dWih, const float* __restrict__ dWhh, const float* __restrict__ db,
    const float* __restrict__ attnW, const float* __restrict__ outW,
    const float* __restrict__ encH,
    float* __restrict__ decH, float* __restrict__ Pbuf, float* __restrict__ y2buf)
{
  __shared__ __align__(16) float smem[12416];   // 48.5 KB, overlaid per path
  const int tid = threadIdx.x;

  if (blockIdx.x < 64) {
    // ---- decoder LSTM ----
    const int b = blockIdx.x;
    const int q = tid & 7;
    const int i = tid >> 3;
    float* xs           = smem;                          // 1536 floats
    float (*hbuf)[160]  = (float(*)[160])(smem + 1536);  // 320 floats
    float* hist         = smem + 1856;                   // 8192 floats

    if (tid < (TT * FIN / 4))
      ((float4*)xs)[tid] = ((const float4*)(x + (size_t)b * TT * FIN))[tid];
    if (tid < 128) {  // h0 = hT = encH row 127, skewed into hbuf[0]
      float hv = encH[((size_t)b * TT + 127) * HH + tid];
      hbuf[0][(tid >> 4) * 20 + (tid & 15)] = hv;
    }
    float c = 0.0f;
    if (q == 0) c = decH[(size_t)b * TT * HH + i];   // c0 = cT (stashed by enc)

    lstm_phase(dWih, dWhh, db, decH + (size_t)b * TT * HH, xs, hbuf, hist, tid, q, i, c);
  } else if (blockIdx.x < 192) {
    // ---- P projection (64-row tile) ----
    const int pb = blockIdx.x - 64;
    const int b  = pb & 63;
    const int r0 = (pb >> 6) * 64;
    float* WT = smem;          // [32][132] padded k-major W2^T quarter, 4224 floats
    float* Xt = smem + 4224;   // [64][128] encH tile, 8192 floats

    const float* X = encH + ((size_t)b * TT + r0) * HH;
    ((float4*)Xt)[tid]        = ((const float4*)X)[tid];
    ((float4*)Xt)[tid + 1024] = ((const float4*)X)[tid + 1024];

    const float* W = attnW + HH;   // W2 = attnW[:, H:2H], row stride 2H
    const int hq = tid & 31, rr = tid >> 5;   // rr 0..31 -> rows 2rr, 2rr+1
    const int h0 = 4 * hq;

    float4 acc0 = make_float4(0.f, 0.f, 0.f, 0.f);
    float4 acc1 = acc0;

    #pragma unroll 1
    for (int kb = 0; kb < 4; ++kb) {
      __syncthreads();
      { // stage 128h x 32k quarter, transposed, padded stride 132
        int h = tid >> 3, koff = (tid & 7) * 4;
        float4 v = *(const float4*)(W + h * 256 + kb * 32 + koff);
        WT[(koff + 0) * 132 + h] = v.x;
        WT[(koff + 1) * 132 + h] = v.y;
        WT[(koff + 2) * 132 + h] = v.z;
        WT[(koff + 3) * 132 + h] = v.w;
      }
      __syncthreads();
      const float* xr0 = Xt + (2 * rr) * 128 + kb * 32;
      const float* xr1 = xr0 + 128;
      #pragma unroll
      for (int k4 = 0; k4 < 32; k4 += 4) {
        float4 xa = *(const float4*)(xr0 + k4);
        float4 xb = *(const float4*)(xr1 + k4);
        float4 w0 = *(const float4*)&WT[(k4 + 0) * 132 + h0];
        float4 w1 = *(const float4*)&WT[(k4 + 1) * 132 + h0];
        float4 w2 = *(const float4*)&WT[(k4 + 2) * 132 + h0];
        float4 w3 = *(const float4*)&WT[(k4 + 3) * 132 + h0];
        FMA4S(acc0, xa.x, w0); FMA4S(acc0, xa.y, w1);
        FMA4S(acc0, xa.z, w2); FMA4S(acc0, xa.w, w3);
        FMA4S(acc1, xb.x, w0); FMA4S(acc1, xb.y, w1);
        FMA4S(acc1, xb.z, w2); FMA4S(acc1, xb.w, w3);
      }
    }
    acc0.x = fexp2(TWO_LOG2E * acc0.x); acc0.y = fexp2(TWO_LOG2E * acc0.y);
    acc0.z = fexp2(TWO_LOG2E * acc0.z); acc0.w = fexp2(TWO_LOG2E * acc0.w);
    acc1.x = fexp2(TWO_LOG2E * acc1.x); acc1.y = fexp2(TWO_LOG2E * acc1.y);
    acc1.z = fexp2(TWO_LOG2E * acc1.z); acc1.w = fexp2(TWO_LOG2E * acc1.w);
    float* O = Pbuf + ((size_t)b * TT + r0) * HH;
    *(float4*)(O + (2 * rr) * 128 + h0)     = acc0;
    *(float4*)(O + (2 * rr + 1) * 128 + h0) = acc1;
  } else if (y2buf) {
    // ---- y2 = encH @ outW2^T, one block per b (hidden under decoder) ----
    const int b = blockIdx.x - 192;
    float* w2l = smem;   // [12][132] outW2 rows, padded
    if (tid < 384) {
      int f = tid >> 5, k = (tid & 31) * 4;
      float4 wv = *(const float4*)(outW + f * 256 + 128 + k);
      *(float4*)&w2l[f * 132 + k] = wv;
    }
    __syncthreads();
    for (int j = tid; j < TT * 12; j += 1024) {
      int t = j / 12, f = j - 12 * t;
      const float* er = encH + ((size_t)b * TT + t) * HH;   // 12 lanes share a row (L1)
      const float* wr = w2l + f * 132;
      float a = 0.f;
      #pragma unroll 8
      for (int k = 0; k < 32; ++k) {
        float4 ev = *(const float4*)(er + 4 * k);
        float4 wv = *(const float4*)(wr + 4 * k);
        ACC4(ev, wv, a);
      }
      y2buf[b * (TT * 16) + t * 16 + f] = a;
    }
  }
}

// ---------------------------------------------------------------------------
// K2 (fallback only): Ea -> Abuf.  Used when workspace lacks y2buf room.
// ---------------------------------------------------------------------------
__global__ __launch_bounds__(256, 2) void projA_kernel(
    const float* __restrict__ decH, const float* __restrict__ attnW,
    const float* __restrict__ attnb, float* __restrict__ Abuf)
{
  const int b  = blockIdx.x & 63;
  const int r0 = (blockIdx.x >> 6) * 16;
  const int tid = threadIdx.x;

  __shared__ __align__(16) float WT[64 * 128];  // 32 KB: W1^T for a k-half
  __shared__ __align__(16) float Xt[16 * 128];  // 8 KB

  const float* X = decH + ((size_t)b * TT + r0) * HH;
  const float* W = attnW;   // W1 = attnW[:, :H], row stride 2H

  ((float4*)Xt)[tid]       = ((const float4*)X)[tid];
  ((float4*)Xt)[256 + tid] = ((const float4*)X)[256 + tid];

  const int hq = tid & 31, rr = tid >> 5;
  const int h0 = 4 * hq;

  float4 acc0 = *(const float4*)(attnb + h0);
  float4 acc1 = acc0;

  for (int kb = 0; kb < 2; ++kb) {
    __syncthreads();  // protect WT overwrite
    {
      int h = tid >> 1, koff = (tid & 1) * 32;
      #pragma unroll
      for (int j = 0; j < 8; ++j) {
        float4 v = *(const float4*)(W + h * 256 + kb * 64 + koff + 4 * j);
        int kp = koff + 4 * j;
        WT[(kp + 0) * 128 + h] = v.x;
        WT[(kp + 1) * 128 + h] = v.y;
        WT[(kp + 2) * 128 + h] = v.z;
        WT[(kp + 3) * 128 + h] = v.w;
      }
    }
    __syncthreads();
    const float* xr0 = Xt + (2 * rr) * 128 + kb * 64;
    const float* xr1 = xr0 + 128;
    #pragma unroll
    for (int k4 = 0; k4 < 64; k4 += 4) {
      float4 xa = *(const float4*)(xr0 + k4);
      float4 xb = *(const float4*)(xr1 + k4);
      float4 w0 = *(const float4*)&WT[(k4 + 0) * 128 + h0];
      float4 w1 = *(const float4*)&WT[(k4 + 1) * 128 + h0];
      float4 w2 = *(const float4*)&WT[(k4 + 2) * 128 + h0];
      float4 w3 = *(const float4*)&WT[(k4 + 3) * 128 + h0];
      FMA4S(acc0, xa.x, w0); FMA4S(acc0, xa.y, w1);
      FMA4S(acc0, xa.z, w2); FMA4S(acc0, xa.w, w3);
      FMA4S(acc1, xb.x, w0); FMA4S(acc1, xb.y, w1);
      FMA4S(acc1, xb.z, w2); FMA4S(acc1, xb.w, w3);
    }
  }
  acc0.x = fexp2(TWO_LOG2E * acc0.x); acc0.y = fexp2(TWO_LOG2E * acc0.y);
  acc0.z = fexp2(TWO_LOG2E * acc0.z); acc0.w = fexp2(TWO_LOG2E * acc0.w);
  acc1.x = fexp2(TWO_LOG2E * acc1.x); acc1.y = fexp2(TWO_LOG2E * acc1.y);
  acc1.z = fexp2(TWO_LOG2E * acc1.z); acc1.w = fexp2(TWO_LOG2E * acc1.w);
  float* O = Abuf + ((size_t)b * TT + r0) * HH;
  *(float4*)(O + (2 * rr) * 128 + h0)     = acc0;
  *(float4*)(O + (2 * rr + 1) * 128 + h0) = acc1;
}

#define AST 132  // padded row stride for a_lds / sc
#define Y2ST 20  // padded row stride for y2 (12 cols used)

// ---------------------------------------------------------------------------
// K3 v8 (main path): fused A-projection + attention + output, 1024 threads.
// 256 blocks x 1024 thr, 32 s-rows/block, 156.5 KB LDS -> 1 block/CU with
// 16 waves (round 9's 8-wave config halved CU wave occupancy vs round 8 and
// was the suspected cancel of the fusion win).  Both Ep halves staged ONCE
// up-front (64 KB buf); W1^T gets its own padded buffer so Ea and Ep don't
// collide; energy thread owns (s, t-half, t-quad) = 4 scores (half of round
// 9's serial work, 2x threads); softmax over 32-lane groups; 6 barriers.
// Ea dot order bitwise-identical to round 9 (absmax must stay 4.88e-4).
// ---------------------------------------------------------------------------
__global__ __launch_bounds__(1024, 4) void attn_fused2_kernel(
    const float* __restrict__ decH, const float* __restrict__ Pbuf,
    const float* __restrict__ y2buf,
    const float* __restrict__ attnW, const float* __restrict__ attnb,
    const float* __restrict__ vw, const float* __restrict__ outW,
    const float* __restrict__ outb, float* __restrict__ out)
{
  const int b  = blockIdx.x >> 2;
  const int s0 = (blockIdx.x & 2) * 16 + (blockIdx.x & 1) * 32 * 2;  // see note
  // note: (blockIdx.x & 3) * 32 written obscurely above -- use plain form:
  const int s0p = (blockIdx.x & 3) * 32;
  const int tid = threadIdx.x;

  __shared__ __align__(16) float buf[128 * 128];   // 64 KB: Ep^T both halves (swizzled)
  __shared__ __align__(16) float w1t[64 * 132];    // 33 KB: W1^T k-half, padded
  __shared__ __align__(16) float a_lds[32 * AST];  // 16.5 KB: Ea tile
  __shared__ __align__(16) float sc[32 * AST];     // 16.5 KB: softmax weights
  __shared__ __align__(16) float dh[32 * 128];     // 16 KB: decH tile
  __shared__ __align__(16) float y2s[TT * Y2ST];   // 10 KB
  __shared__ __align__(16) float vl[HH];

  (void)s0;
  // ---- stage dh, vl, y2, and BOTH Ep halves (transposed+swizzled) ----
  ((float4*)dh)[tid] = ((const float4*)(decH + ((size_t)b * TT + s0p) * HH))[tid];
  if (tid < 32) ((float4*)vl)[tid] = ((const float4*)vw)[tid];
  if (tid < 512) {
    float4 v = ((const float4*)(y2buf + (size_t)b * (TT * 16)))[tid];
    int t = tid >> 2, g = (tid & 3) * 4;
    *(float4*)&y2s[t * Y2ST + g] = v;
  }
  #pragma unroll
  for (int i = 0; i < 4; ++i) {
    int flat = i * 4096 + tid * 4;
    int tp = flat >> 7;          // 0..127 (full t)
    int h0f = flat & 127;
    float4 v = *(const float4*)(Pbuf + ((size_t)b * TT + tp) * HH + h0f);
    int hf = tp >> 6, tpl = tp & 63, tq = tpl >> 2, tr = tpl & 3;
    int base = hf * 64 + tr;
    buf[(h0f + 0) * 128 + base + 4 * ((tq ^ ((h0f + 0) >> 2)) & 15)] = v.x;
    buf[(h0f + 1) * 128 + base + 4 * ((tq ^ ((h0f + 1) >> 2)) & 15)] = v.y;
    buf[(h0f + 2) * 128 + base + 4 * ((tq ^ ((h0f + 2) >> 2)) & 15)] = v.z;
    buf[(h0f + 3) * 128 + base + 4 * ((tq ^ ((h0f + 3) >> 2)) & 15)] = v.w;
  }

  // ---- Ea = exp2(2log2e*(dh @ W1^T + attn_b)); 512 threads, 2 rows each ----
  {
    const int hq = tid & 31, rr = (tid >> 5) & 15;
    const int h0 = 4 * hq;
    float4 acc0 = *(const float4*)(attnb + h0);
    float4 acc1 = acc0;
    #pragma unroll 1
    for (int kb = 0; kb < 2; ++kb) {
      __syncthreads();  // kb0: all staging done; kb1: protect w1t overwrite
      {
        // stage W1^T k-half: 128 h x 64 k -> w1t[k][h] (padded 132), 1024 thr
        int h = tid >> 3, koff = (tid & 7) * 8;
        #pragma unroll
        for (int j = 0; j < 2; ++j) {
          float4 v = *(const float4*)(attnW + h * 256 + kb * 64 + koff + 4 * j);
          int kp = koff + 4 * j;
          w1t[(kp + 0) * 132 + h] = v.x;
          w1t[(kp + 1) * 132 + h] = v.y;
          w1t[(kp + 2) * 132 + h] = v.z;
          w1t[(kp + 3) * 132 + h] = v.w;
        }
      }
      __syncthreads();
      if (tid < 512) {
        const float* xr0 = dh + (2 * rr) * 128 + kb * 64;
        const float* xr1 = xr0 + 128;
        #pragma unroll
        for (int k4 = 0; k4 < 64; k4 += 4) {
          float4 xa = *(const float4*)(xr0 + k4);
          float4 xb = *(const float4*)(xr1 + k4);
          float4 w0 = *(const float4*)&w1t[(k4 + 0) * 132 + h0];
          float4 w1 = *(const float4*)&w1t[(k4 + 1) * 132 + h0];
          float4 w2 = *(const float4*)&w1t[(k4 + 2) * 132 + h0];
          float4 w3 = *(const float4*)&w1t[(k4 + 3) * 132 + h0];
          FMA4S(acc0, xa.x, w0); FMA4S(acc0, xa.y, w1);
          FMA4S(acc0, xa.z, w2); FMA4S(acc0, xa.w, w3);
          FMA4S(acc1, xb.x, w0); FMA4S(acc1, xb.y, w1);
          FMA4S(acc1, xb.z, w2); FMA4S(acc1, xb.w, w3);
        }
      }
    }
    if (tid < 512) {
      acc0.x = fexp2(TWO_LOG2E * acc0.x); acc0.y = fexp2(TWO_LOG2E * acc0.y);
      acc0.z = fexp2(TWO_LOG2E * acc0.z); acc0.w = fexp2(TWO_LOG2E * acc0.w);
      acc1.x = fexp2(TWO_LOG2E * acc1.x); acc1.y = fexp2(TWO_LOG2E * acc1.y);
      acc1.z = fexp2(TWO_LOG2E * acc1.z); acc1.w = fexp2(TWO_LOG2E * acc1.w);
      *(float4*)&a_lds[(2 * rr) * AST + h0]     = acc0;
      *(float4*)&a_lds[(2 * rr + 1) * AST + h0] = acc1;
    }
  }
  __syncthreads();  // a_lds ready; w1t no longer needed; buf (Ep) ready

  // ---- energies: thread = (s, t-half, t-quad), 4 scores over all 128 h ----
  const int es  = tid >> 5;          // 0..31 s-row
  const int ehf = (tid >> 4) & 1;    // t-half
  const int euq = tid & 15;          // t-quad within half
  float4 acc = make_float4(0.f, 0.f, 0.f, 0.f);
  {
    const float* earow = a_lds + es * AST;
    #pragma unroll 4
    for (int h = 0; h < 128; h += 4) {
      float4 ea = *(const float4*)&earow[h];
      float4 va = *(const float4*)&vl[h];
      const int xoff = ehf * 64 + 4 * ((euq ^ ((h >> 2) & 15)) & 15);
      float4 p0 = *(const float4*)&buf[(h + 0) * 128 + xoff];
      float4 p1 = *(const float4*)&buf[(h + 1) * 128 + xoff];
      float4 p2 = *(const float4*)&buf[(h + 2) * 128 + xoff];
      float4 p3 = *(const float4*)&buf[(h + 3) * 128 + xoff];
      acc.x = fmaf(va.x, frcp(fmaf(ea.x, p0.x, 1.f)), acc.x);
      acc.y = fmaf(va.x, frcp(fmaf(ea.x, p0.y, 1.f)), acc.y);
      acc.z = fmaf(va.x, frcp(fmaf(ea.x, p0.z, 1.f)), acc.z);
      acc.w = fmaf(va.x, frcp(fmaf(ea.x, p0.w, 1.f)), acc.w);
      acc.x = fmaf(va.y, frcp(fmaf(ea.y, p1.x, 1.f)), acc.x);
      acc.y = fmaf(va.y, frcp(fmaf(ea.y, p1.y, 1.f)), acc.y);
      acc.z = fmaf(va.y, frcp(fmaf(ea.y, p1.z, 1.f)), acc.z);
      acc.w = fmaf(va.y, frcp(fmaf(ea.y, p1.w, 1.f)), acc.w);
      acc.x = fmaf(va.z, frcp(fmaf(ea.z, p2.x, 1.f)), acc.x);
      acc.y = fmaf(va.z, frcp(fmaf(ea.z, p2.y, 1.f)), acc.y);
      acc.z = fmaf(va.z, frcp(fmaf(ea.z, p2.z, 1.f)), acc.z);
      acc.w = fmaf(va.z, frcp(fmaf(ea.z, p2.w, 1.f)), acc.w);
      acc.x = fmaf(va.w, frcp(fmaf(ea.w, p3.x, 1.f)), acc.x);
      acc.y = fmaf(va.w, frcp(fmaf(ea.w, p3.y, 1.f)), acc.y);
      acc.z = fmaf(va.w, frcp(fmaf(ea.w, p3.z, 1.f)), acc.z);
      acc.w = fmaf(va.w, frcp(fmaf(ea.w, p3.w, 1.f)), acc.w);
    }
    acc.x = -2.f * acc.x; acc.y = -2.f * acc.y;
    acc.z = -2.f * acc.z; acc.w = -2.f * acc.w;
  }

  // ---- softmax over t: row's 128 scores live in a 32-lane group ----
  {
    float mx = fmaxf(fmaxf(acc.x, acc.y), fmaxf(acc.z, acc.w));
    #pragma unroll
    for (int msk = 1; msk <= 16; msk <<= 1) mx = fmaxf(mx, __shfl_xor(mx, msk, 64));
    float4 e;
    e.x = fexp2(LOG2E * (acc.x - mx));
    e.y = fexp2(LOG2E * (acc.y - mx));
    e.z = fexp2(LOG2E * (acc.z - mx));
    e.w = fexp2(LOG2E * (acc.w - mx));
    float sm = (e.x + e.y) + (e.z + e.w);
    #pragma unroll
    for (int msk = 1; msk <= 16; msk <<= 1) sm += __shfl_xor(sm, msk, 64);
    float r = frcp(sm);
    e.x *= r; e.y *= r; e.z *= r; e.w *= r;
    *(float4*)&sc[es * AST + ehf * 64 + 4 * euq] = e;
  }
  __syncthreads();  // sc complete

  // ---- out[b,s,f] = outb[f] + dh[s,:]·outW1[f,:] + sc[s,:]·y2[:,f] ----
  if (tid < 384) {
    int s = tid / 12, f = tid - 12 * (tid / 12);
    float acco = outb[f];
    const float4* w4 = (const float4*)(outW + f * 256);  // outW1 row (global/L1)
    const float4* d4 = (const float4*)(dh + s * 128);
    #pragma unroll
    for (int k = 0; k < 32; ++k) {
      float4 wv = w4[k], dv = d4[k];
      acco = fmaf(wv.x, dv.x, acco); acco = fmaf(wv.y, dv.y, acco);
      acco = fmaf(wv.z, dv.z, acco); acco = fmaf(wv.w, dv.w, acco);
    }
    const float* wrow = sc + s * AST;
    #pragma unroll 8
    for (int t = 0; t < TT; ++t)
      acco = fmaf(wrow[t], y2s[t * Y2ST + f], acco);
    out[((size_t)b * TT + s0p + s) * FIN + f] = acco;
  }
}

// ---------------------------------------------------------------------------
// K3 fallback (no y2 workspace): round-7 structure, 512 blocks x 16 rows.
// ---------------------------------------------------------------------------
__global__ __launch_bounds__(512, 2) void attn_kernel_fb(
    const float* __restrict__ encH, const float* __restrict__ decH,
    const float* __restrict__ Pbuf, const float* __restrict__ Abuf,
    const float* __restrict__ vw, const float* __restrict__ outW,
    const float* __restrict__ outb, float* __restrict__ out)
{
  const int b  = blockIdx.x >> 3;
  const int s0 = (blockIdx.x & 7) * 16;
  const int tid = threadIdx.x;

  __shared__ __align__(16) float buf[64 * 128];
  __shared__ __align__(16) float a_lds[16 * AST];
  __shared__ __align__(16) float sc[16 * AST];
  __shared__ __align__(16) float dh[16 * 128];
  __shared__ __align__(16) float vl[HH];
  __shared__ __align__(16) float y2s[TT * Y2ST];
  __shared__ __align__(16) float w2l[12 * AST];

  ((float4*)dh)[tid] = ((const float4*)(decH + ((size_t)b * TT + s0) * HH))[tid];
  if (tid < 32) ((float4*)vl)[tid] = ((const float4*)vw)[tid];
  {
    int r = tid >> 5, c4 = (tid & 31) * 4;
    float4 av = *(const float4*)(Abuf + ((size_t)b * TT + s0 + r) * HH + c4);
    *(float4*)&a_lds[r * AST + c4] = av;
  }
  if (tid < 384) {
    int f = tid >> 5, k = (tid & 31) * 4;
    float4 wv = *(const float4*)(outW + f * 256 + 128 + k);
    *(float4*)&w2l[f * AST + k] = wv;
  }

  const int u  = tid & 31;
  const int sl = tid >> 5;
  const int uq = u & 15;
  const int uh = u >> 4;

  for (int half = 0; half < 2; ++half) {
    const int tbase = half * 64;
    __syncthreads();
    #pragma unroll
    for (int i = 0; i < 4; ++i) {
      int flat = i * 2048 + tid * 4;
      int tp = flat >> 7;
      int h0 = flat & 127;
      float4 v = *(const float4*)(Pbuf + ((size_t)b * TT + tbase + tp) * HH + h0);
      int tq = tp >> 2, tr = tp & 3;
      buf[(h0 + 0) * 64 + 4 * ((tq ^ ((h0 + 0) >> 2)) & 15) + tr] = v.x;
      buf[(h0 + 1) * 64 + 4 * ((tq ^ ((h0 + 1) >> 2)) & 15) + tr] = v.y;
      buf[(h0 + 2) * 64 + 4 * ((tq ^ ((h0 + 2) >> 2)) & 15) + tr] = v.z;
      buf[(h0 + 3) * 64 + 4 * ((tq ^ ((h0 + 3) >> 2)) & 15) + tr] = v.w;
    }
    __syncthreads();
    float4 acc = make_float4(0.f, 0.f, 0.f, 0.f);
    const float* earow = a_lds + sl * AST;
    #pragma unroll 4
    for (int hh = 0; hh < 64; hh += 4) {
      const int h = uh * 64 + hh;
      float4 ea = *(const float4*)&earow[h];
      float4 va = *(const float4*)&vl[h];
      const int xoff = 4 * ((uq ^ ((h >> 2) & 15)) & 15);
      float4 p0 = *(const float4*)&buf[(h + 0) * 64 + xoff];
      float4 p1 = *(const float4*)&buf[(h + 1) * 64 + xoff];
      float4 p2 = *(const float4*)&buf[(h + 2) * 64 + xoff];
      float4 p3 = *(const float4*)&buf[(h + 3) * 64 + xoff];
      acc.x = fmaf(va.x, frcp(fmaf(ea.x, p0.x, 1.f)), acc.x);
      acc.y = fmaf(va.x, frcp(fmaf(ea.x, p0.y, 1.f)), acc.y);
      acc.z = fmaf(va.x, frcp(fmaf(ea.x, p0.z, 1.f)), acc.z);
      acc.w = fmaf(va.x, frcp(fmaf(ea.x, p0.w, 1.f)), acc.w);
      acc.x = fmaf(va.y, frcp(fmaf(ea.y, p1.x, 1.f)), acc.x);
      acc.y = fmaf(va.y, frcp(fmaf(ea.y, p1.y, 1.f)), acc.y);
      acc.z = fmaf(va.y, frcp(fmaf(ea.y, p1.z, 1.f)), acc.z);
      acc.w = fmaf(va.y, frcp(fmaf(ea.y, p1.w, 1.f)), acc.w);
      acc.x = fmaf(va.z, frcp(fmaf(ea.z, p2.x, 1.f)), acc.x);
      acc.y = fmaf(va.z, frcp(fmaf(ea.z, p2.y, 1.f)), acc.y);
      acc.z = fmaf(va.z, frcp(fmaf(ea.z, p2.z, 1.f)), acc.z);
      acc.w = fmaf(va.z, frcp(fmaf(ea.z, p2.w, 1.f)), acc.w);
      acc.x = fmaf(va.w, frcp(fmaf(ea.w, p3.x, 1.f)), acc.x);
      acc.y = fmaf(va.w, frcp(fmaf(ea.w, p3.y, 1.f)), acc.y);
      acc.z = fmaf(va.w, frcp(fmaf(ea.w, p3.z, 1.f)), acc.z);
      acc.w = fmaf(va.w, frcp(fmaf(ea.w, p3.w, 1.f)), acc.w);
    }
    acc.x += __shfl_xor(acc.x, 16, 64);
    acc.y += __shfl_xor(acc.y, 16, 64);
    acc.z += __shfl_xor(acc.z, 16, 64);
    acc.w += __shfl_xor(acc.w, 16, 64);
    if (uh == 0) {
      float4 o;
      o.x = -2.f * acc.x; o.y = -2.f * acc.y;
      o.z = -2.f * acc.z; o.w = -2.f * acc.w;
      *(float4*)&sc[sl * AST + tbase + 4 * uq] = o;
    }
  }
  __syncthreads();

  {
    float4 sv = *(const float4*)&sc[sl * AST + 4 * u];
    float mx = fmaxf(fmaxf(sv.x, sv.y), fmaxf(sv.z, sv.w));
    #pragma unroll
    for (int msk = 1; msk <= 16; msk <<= 1) mx = fmaxf(mx, __shfl_xor(mx, msk, 64));
    float4 e;
    e.x = fexp2(LOG2E * (sv.x - mx));
    e.y = fexp2(LOG2E * (sv.y - mx));
    e.z = fexp2(LOG2E * (sv.z - mx));
    e.w = fexp2(LOG2E * (sv.w - mx));
    float sm = (e.x + e.y) + (e.z + e.w);
    #pragma unroll
    for (int msk = 1; msk <= 16; msk <<= 1) sm += __shfl_xor(sm, msk, 64);
    float r = frcp(sm);
    e.x *= r; e.y *= r; e.z *= r; e.w *= r;
    *(float4*)&sc[sl * AST + 4 * u] = e;
  }

  // y2 in-block (no y2buf)
  for (int half = 0; half < 2; ++half) {
    const int tbase = half * 64;
    __syncthreads();
    #pragma unroll
    for (int i = 0; i < 4; ++i) {
      int flat = i * 2048 + tid * 4;
      int tp = flat >> 7;
      int hh0 = flat & 127;
      *(float4*)&buf[tp * 128 + hh0] =
          *(const float4*)(encH + ((size_t)b * TT + tbase + tp) * HH + hh0);
    }
    __syncthreads();
    {
      int j = tid;
      int t = j / 12, f = j - 12 * t;
      float a = 0.f;
      const float* br = buf + t * 128;
      const float* wr = w2l + f * AST;
      #pragma unroll 8
      for (int k = 0; k < 32; ++k) {
        float4 bv = *(const float4*)(br + 4 * k);
        float4 wv = *(const float4*)(wr + 4 * k);
        ACC4(bv, wv, a);
      }
      y2s[(tbase + t) * Y2ST + f] = a;
      if (tid < 256) {
        int j2 = tid + 512;
        int t2 = j2 / 12, f2 = j2 - 12 * t2;
        float a2 = 0.f;
        const float* br2 = buf + t2 * 128;
        const float* wr2 = w2l + f2 * AST;
        #pragma unroll 8
        for (int k = 0; k < 32; ++k) {
          float4 bv = *(const float4*)(br2 + 4 * k);
          float4 wv = *(const float4*)(wr2 + 4 * k);
          ACC4(bv, wv, a2);
        }
        y2s[(tbase + t2) * Y2ST + f2] = a2;
      }
    }
  }
  __syncthreads();

  if (tid < 192) {
    int s = tid / 12, f = tid - 12 * (tid / 12);
    float acc = outb[f];
    const float4* w4 = (const float4*)(outW + f * 256);
    const float4* d4 = (const float4*)(dh + s * 128);
    #pragma unroll
    for (int k = 0; k < 32; ++k) {
      float4 wv = w4[k], dv = d4[k];
      acc = fmaf(wv.x, dv.x, acc); acc = fmaf(wv.y, dv.y, acc);
      acc = fmaf(wv.z, dv.z, acc); acc = fmaf(wv.w, dv.w, acc);
    }
    const float* wrow = sc + s * AST;
    #pragma unroll 8
    for (int t = 0; t < TT; ++t)
      acc = fmaf(wrow[t], y2s[t * Y2ST + f], acc);
    out[((size_t)b * TT + s0 + s) * FIN + f] = acc;
  }
}

// ---------------------------------------------------------------------------
extern "C" void kernel_launch(void* const* d_in, const int* in_sizes, int n_in,
                              void* d_out, int out_size, void* d_ws, size_t ws_size,
                              hipStream_t stream)
{
  const float* x     = (const float*)d_in[0];
  const float* eWih  = (const float*)d_in[1];
  const float* eWhh  = (const float*)d_in[2];
  const float* eb    = (const float*)d_in[3];
  const float* dWih  = (const float*)d_in[4];
  const float* dWhh  = (const float*)d_in[5];
  const float* db    = (const float*)d_in[6];
  const float* attnW = (const float*)d_in[7];
  const float* attnb = (const float*)d_in[8];
  const float* vw    = (const float*)d_in[9];
  const float* outW  = (const float*)d_in[10];
  const float* outb  = (const float*)d_in[11];
  float* out = (float*)d_out;

  float* ws   = (float*)d_ws;
  const size_t SEG = (size_t)BB * TT * HH;  // 1,048,576 floats = 4 MB
  float* encH = ws;
  float* decH = ws + SEG;
  float* Pbuf = ws + 2 * SEG;   // Ep = exp2(2log2e * P)
  float* Abuf = ws + 3 * SEG;   // fallback only
  float* y2buf = ws + 4 * SEG;  // [BB][TT][16] y2

  const size_t need_bytes = (4 * SEG + (size_t)BB * TT * 16) * sizeof(float);
  const bool have_y2 = ws_size >= need_bytes;

  lstm_enc_kernel<<<64, 1024, 0, stream>>>(x, eWih, eWhh, eb, encH, decH);
  if (have_y2) {
    lstm_dec_p_kernel<<<256, 1024, 0, stream>>>(x, dWih, dWhh, db, attnW, outW,
                                                encH, decH, Pbuf, y2buf);
    attn_fused2_kernel<<<256, 1024, 0, stream>>>(decH, Pbuf, y2buf, attnW, attnb,
                                                 vw, outW, outb, out);
  } else {
    lstm_dec_p_kernel<<<192, 1024, 0, stream>>>(x, dWih, dWhh, db, attnW, outW,
                                                encH, decH, Pbuf, nullptr);
    projA_kernel<<<512, 256, 0, stream>>>(decH, attnW, attnb, Abuf);
    attn_kernel_fb<<<512, 512, 0, stream>>>(encH, decH, Pbuf, Abuf,
                                            vw, outW, outb, out);
  }
}